// Round 5
// baseline (313.483 us; speedup 1.0000x reference)
//
#include <hip/hip_runtime.h>
#include <math.h>

#define BB 128
#define CIN 512
#define HW 64
#define OUTC 256
#define EMB 4096
#define DDIM 4096
#define ES 32
#define QCH 16          // D-chunks in k_main

// workspace layout (float offsets)
#define FT_OFF    0          // 8192*256
#define ENC_OFF   2097152    // 8192 ints
#define PL_OFF    2105344    // 128*16*64 = 131072
#define PD_OFF    2236416
#define PT_OFF    2367488
#define PTL_OFF   2498560

typedef short short8 __attribute__((ext_vector_type(8)));
typedef float floatx4 __attribute__((ext_vector_type(4)));

__device__ __forceinline__ unsigned short f2bf(float f) {
    unsigned int u = __builtin_bit_cast(unsigned int, f);
    u += 0x7FFFu + ((u >> 16) & 1u);          // RNE; inputs are finite
    return (unsigned short)(u >> 16);
}

// ---------------- K1: ft = feat . W^T + bias, via bf16 MFMA -----------------
// block: (batch nb, o-tile ob) -> 64 pixels x 64 outputs. 4 waves, each 64p x 16o.
// k-permutation psi: slot s=8q+j <-> c = (s>>1) + 16*(s&1), applied to BOTH
// fragments so the MFMA dot product is unchanged.
__global__ __launch_bounds__(256) void k_lda(const float* __restrict__ feat,
                                             const float* __restrict__ w,
                                             const float* __restrict__ bias,
                                             float* __restrict__ ft,
                                             float* __restrict__ out) {
    if (blockIdx.x == 0 && threadIdx.x == 0) *out = 0.f;   // zero loss accumulator
    __shared__ unsigned short As[64 * 40];    // row p: 32 slots used, stride 40
    int bx = blockIdx.x;
    int nb = bx >> 2, ob = bx & 3;
    int n0 = nb * 64, o0 = ob * 64;
    int tid = threadIdx.x;
    int lane = tid & 63, wid = tid >> 6;
    int m = lane & 15, q = lane >> 4;         // m -> col-in-frag, q -> k-quad
    int cc = tid >> 4;                        // 0..15  (staging: c and c+16)
    int p4 = (tid & 15) * 4;                  // staging: 4 consecutive pixels
    const float* fbase = feat + (size_t)nb * CIN * HW;
    const float* wrow  = w + (size_t)(o0 + wid * 16 + m) * CIN;
    floatx4 acc[4] = {};
    for (int kt = 0; kt < 16; ++kt) {
        int k0 = kt * 32;
        float4 v0 = *(const float4*)(fbase + (size_t)(k0 + cc) * HW + p4);
        float4 v1 = *(const float4*)(fbase + (size_t)(k0 + cc + 16) * HW + p4);
        float4 w0 = *(const float4*)(wrow + k0 + 4 * q);
        float4 w1 = *(const float4*)(wrow + k0 + 16 + 4 * q);
        short8 bf;
        bf[0] = (short)f2bf(w0.x); bf[1] = (short)f2bf(w1.x);
        bf[2] = (short)f2bf(w0.y); bf[3] = (short)f2bf(w1.y);
        bf[4] = (short)f2bf(w0.z); bf[5] = (short)f2bf(w1.z);
        bf[6] = (short)f2bf(w0.w); bf[7] = (short)f2bf(w1.w);
        ushort2 pk;
        pk.x = f2bf(v0.x); pk.y = f2bf(v1.x);
        *(ushort2*)&As[(p4 + 0) * 40 + 2 * cc] = pk;
        pk.x = f2bf(v0.y); pk.y = f2bf(v1.y);
        *(ushort2*)&As[(p4 + 1) * 40 + 2 * cc] = pk;
        pk.x = f2bf(v0.z); pk.y = f2bf(v1.z);
        *(ushort2*)&As[(p4 + 2) * 40 + 2 * cc] = pk;
        pk.x = f2bf(v0.w); pk.y = f2bf(v1.w);
        *(ushort2*)&As[(p4 + 3) * 40 + 2 * cc] = pk;
        __syncthreads();
#pragma unroll
        for (int mt = 0; mt < 4; ++mt) {
            short8 af = *(short8*)&As[(mt * 16 + m) * 40 + q * 8];
            acc[mt] = __builtin_amdgcn_mfma_f32_16x16x32_bf16(af, bf, acc[mt], 0, 0, 0);
        }
        __syncthreads();
    }
    float bv = bias[o0 + wid * 16 + m];
#pragma unroll
    for (int mt = 0; mt < 4; ++mt)
#pragma unroll
        for (int r = 0; r < 4; ++r) {
            int p = mt * 16 + q * 4 + r;      // C/D: row = quad*4+reg, col = lane&15
            ft[(size_t)(n0 + p) * OUTC + o0 + wid * 16 + m] = acc[mt][r] + bv;
        }
}

// ---------------- K2: enc[n] = cls*32 + argmin_j ||ft_n - c_j||^2 -----------
__global__ __launch_bounds__(256) void k_enc(const float* __restrict__ ft,
                                             const float* __restrict__ cc,
                                             const int* __restrict__ labels,
                                             int* __restrict__ enc) {
    __shared__ __align__(16) float cbuf[ES * OUTC];   // 32 KB
    __shared__ float vred[4 * 64];
    __shared__ int   ired[4 * 64];
    int b = blockIdx.x, tid = threadIdx.x;
    int cls = labels[b];
    const float* cbase = cc + (size_t)cls * ES * OUTC;
    for (int i = tid * 4; i < ES * OUTC; i += 256 * 4)
        *(float4*)&cbuf[i] = *(const float4*)&cbase[i];
    __syncthreads();
    int p = tid & 63, jg = tid >> 6;
    const float* xrow = ft + (size_t)(b * 64 + p) * OUTC;
    float sc[8];
#pragma unroll
    for (int jj = 0; jj < 8; ++jj) sc[jj] = 0.f;
    for (int o = 0; o < OUTC; o += 4) {
        float4 x4 = *(const float4*)&xrow[o];
        float m0 = -2.f * x4.x, m1 = -2.f * x4.y, m2 = -2.f * x4.z, m3 = -2.f * x4.w;
#pragma unroll
        for (int jj = 0; jj < 8; ++jj) {
            float4 c4 = *(const float4*)&cbuf[(jg * 8 + jj) * OUTC + o];
            float s = sc[jj];
            s = fmaf(c4.x, c4.x + m0, s);
            s = fmaf(c4.y, c4.y + m1, s);
            s = fmaf(c4.z, c4.z + m2, s);
            s = fmaf(c4.w, c4.w + m3, s);
            sc[jj] = s;
        }
    }
    float best = sc[0]; int bj = jg * 8;
#pragma unroll
    for (int jj = 1; jj < 8; ++jj)
        if (sc[jj] < best) { best = sc[jj]; bj = jg * 8 + jj; }
    vred[jg * 64 + p] = best;
    ired[jg * 64 + p] = bj;
    __syncthreads();
    if (tid < 64) {
        float bv = vred[tid]; int bi = ired[tid];
#pragma unroll
        for (int g = 1; g < 4; ++g) {
            float v = vred[g * 64 + tid];
            if (v < bv) { bv = v; bi = ired[g * 64 + tid]; }
        }
        enc[b * 64 + tid] = cls * ES + bi;
    }
}

// ---------------- K4a: one pass over scores + teacher gather ----------------
// Per (b, d-chunk): per-pixel partial sumexp(s), dot(t,s), sum(t), sum(t*log t).
// The teacher row stats ride on the same loads the dot needs (rowsum fused).
__global__ __launch_bounds__(256) void k_main(const float* __restrict__ scores,
                                              const float* __restrict__ ts,
                                              const int* __restrict__ enc,
                                              float* __restrict__ pl,
                                              float* __restrict__ pd,
                                              float* __restrict__ pt,
                                              float* __restrict__ ptl) {
    __shared__ float redl[4 * 64];
    __shared__ float redd[4 * 64];
    __shared__ float redt[4 * 64];
    __shared__ float redtl[4 * 64];
    int bx = blockIdx.x;
    int b = bx >> 4, q = bx & 15;
    int tid = threadIdx.x;
    int lane = tid & 63, wv = tid >> 6;
    int pg = lane & 15, lg = lane >> 4;
    const int* eb = enc + b * 64 + pg * 4;
    int e0 = eb[0], e1 = eb[1], e2 = eb[2], e3 = eb[3];
    int d0 = q * 256 + wv * 4 + lg;
    const float* sptr = scores + (size_t)b * DDIM * HW + (size_t)d0 * HW + pg * 4;
    const float* t0 = ts + (size_t)e0 * DDIM + d0;
    const float* t1 = ts + (size_t)e1 * DDIM + d0;
    const float* t2 = ts + (size_t)e2 * DDIM + d0;
    const float* t3 = ts + (size_t)e3 * DDIM + d0;
    float l0 = 0.f, l1 = 0.f, l2 = 0.f, l3 = 0.f;
    float x0 = 0.f, x1 = 0.f, x2 = 0.f, x3 = 0.f;
    float s0 = 0.f, s1 = 0.f, s2 = 0.f, s3 = 0.f;
    float y0 = 0.f, y1 = 0.f, y2 = 0.f, y3 = 0.f;
#pragma unroll
    for (int it = 0; it < 16; ++it) {
        float4 s4 = *(const float4*)(sptr + (size_t)it * 16 * HW);
        float tv0 = t0[it * 16];
        float tv1 = t1[it * 16];
        float tv2 = t2[it * 16];
        float tv3 = t3[it * 16];
        l0 += __expf(s4.x);
        l1 += __expf(s4.y);
        l2 += __expf(s4.z);
        l3 += __expf(s4.w);
        x0 = fmaf(tv0, s4.x, x0);
        x1 = fmaf(tv1, s4.y, x1);
        x2 = fmaf(tv2, s4.z, x2);
        x3 = fmaf(tv3, s4.w, x3);
        s0 += tv0; s1 += tv1; s2 += tv2; s3 += tv3;
        y0 += (tv0 > 0.f) ? tv0 * __logf(tv0) : 0.f;
        y1 += (tv1 > 0.f) ? tv1 * __logf(tv1) : 0.f;
        y2 += (tv2 > 0.f) ? tv2 * __logf(tv2) : 0.f;
        y3 += (tv3 > 0.f) ? tv3 * __logf(tv3) : 0.f;
    }
    l0 += __shfl_xor(l0, 16); l0 += __shfl_xor(l0, 32);
    l1 += __shfl_xor(l1, 16); l1 += __shfl_xor(l1, 32);
    l2 += __shfl_xor(l2, 16); l2 += __shfl_xor(l2, 32);
    l3 += __shfl_xor(l3, 16); l3 += __shfl_xor(l3, 32);
    x0 += __shfl_xor(x0, 16); x0 += __shfl_xor(x0, 32);
    x1 += __shfl_xor(x1, 16); x1 += __shfl_xor(x1, 32);
    x2 += __shfl_xor(x2, 16); x2 += __shfl_xor(x2, 32);
    x3 += __shfl_xor(x3, 16); x3 += __shfl_xor(x3, 32);
    s0 += __shfl_xor(s0, 16); s0 += __shfl_xor(s0, 32);
    s1 += __shfl_xor(s1, 16); s1 += __shfl_xor(s1, 32);
    s2 += __shfl_xor(s2, 16); s2 += __shfl_xor(s2, 32);
    s3 += __shfl_xor(s3, 16); s3 += __shfl_xor(s3, 32);
    y0 += __shfl_xor(y0, 16); y0 += __shfl_xor(y0, 32);
    y1 += __shfl_xor(y1, 16); y1 += __shfl_xor(y1, 32);
    y2 += __shfl_xor(y2, 16); y2 += __shfl_xor(y2, 32);
    y3 += __shfl_xor(y3, 16); y3 += __shfl_xor(y3, 32);
    if (lg == 0) {
        int o = wv * 64 + pg * 4;
        redl[o + 0] = l0;  redl[o + 1] = l1;  redl[o + 2] = l2;  redl[o + 3] = l3;
        redd[o + 0] = x0;  redd[o + 1] = x1;  redd[o + 2] = x2;  redd[o + 3] = x3;
        redt[o + 0] = s0;  redt[o + 1] = s1;  redt[o + 2] = s2;  redt[o + 3] = s3;
        redtl[o + 0] = y0; redtl[o + 1] = y1; redtl[o + 2] = y2; redtl[o + 3] = y3;
    }
    __syncthreads();
    if (tid < 64) {
        float L = redl[tid] + redl[64 + tid] + redl[128 + tid] + redl[192 + tid];
        float D = redd[tid] + redd[64 + tid] + redd[128 + tid] + redd[192 + tid];
        float T = redt[tid] + redt[64 + tid] + redt[128 + tid] + redt[192 + tid];
        float Y = redtl[tid] + redtl[64 + tid] + redtl[128 + tid] + redtl[192 + tid];
        int idx = (b * QCH + q) * 64 + tid;
        pl[idx] = L;
        pd[idx] = D;
        pt[idx] = T;
        ptl[idx] = Y;
    }
}

// ---------------- K4b: merge partials, final loss ---------------------------
__global__ __launch_bounds__(64) void k_final(const float* __restrict__ pl,
                                              const float* __restrict__ pd,
                                              const float* __restrict__ pt,
                                              const float* __restrict__ ptl,
                                              float* __restrict__ out) {
    int b = blockIdx.x, p = threadIdx.x;
    int base = b * QCH * 64 + p;
    float L = 0.f, D = 0.f, T = 0.f, Y = 0.f;
#pragma unroll
    for (int q = 0; q < QCH; ++q) {
        L += pl[base + q * 64];
        D += pd[base + q * 64];
        T += pt[base + q * 64];
        Y += ptl[base + q * 64];
    }
    float lse = logf(L);
    float row = Y - D + T * lse;
    for (int off = 32; off; off >>= 1) row += __shfl_down(row, off);
    if (p == 0) atomicAdd(out, row * (1.f / 8192.f));
}

extern "C" void kernel_launch(void* const* d_in, const int* in_sizes, int n_in,
                              void* d_out, int out_size, void* d_ws, size_t ws_size,
                              hipStream_t stream) {
    const float* feat   = (const float*)d_in[0];
    const float* scores = (const float*)d_in[1];
    const int*   labels = (const int*)d_in[2];
    const float* ldaw   = (const float*)d_in[3];
    const float* ldab   = (const float*)d_in[4];
    const float* cc     = (const float*)d_in[5];
    const float* ts     = (const float*)d_in[6];
    float* out = (float*)d_out;
    float* ws  = (float*)d_ws;

    float* ft    = ws + FT_OFF;
    int*   enc   = (int*)(ws + ENC_OFF);
    float* pl    = ws + PL_OFF;
    float* pd    = ws + PD_OFF;
    float* pt    = ws + PT_OFF;
    float* ptl   = ws + PTL_OFF;

    k_lda   <<<512,  256, 0, stream>>>(feat, ldaw, ldab, ft, out);
    k_enc   <<<BB,   256, 0, stream>>>(ft, cc, labels, enc);
    k_main  <<<BB * QCH, 256, 0, stream>>>(scores, ts, enc, pl, pd, pt, ptl);
    k_final <<<BB,    64, 0, stream>>>(pl, pd, pt, ptl, out);
}